// Round 6
// baseline (1000.777 us; speedup 1.0000x reference)
//
#include <hip/hip_runtime.h>
#include <hip/hip_bf16.h>
#include <stdint.h>

// Problem constants (match setup_inputs)
#define M_ROWS 100352   // 2048 * 49
#define C_DIM  512
#define QKV_N  1536
#define NH     16
#define HD     32
#define NWIN   49       // window tokens (7*7)
#define NMASK  64

typedef __attribute__((ext_vector_type(4))) float        f32x4;
typedef __attribute__((ext_vector_type(8))) short        bf16x8;
typedef __attribute__((ext_vector_type(4))) unsigned int u32x4;

static __device__ __forceinline__ unsigned short f32_to_bf16(float f) {
  union { float f; unsigned int u; } v; v.f = f;
  unsigned int u = v.u;
  return (unsigned short)((u + 0x7FFFu + ((u >> 16) & 1u)) >> 16);  // RNE
}

// ---------------------------------------------------------------- k_cvt
__global__ void k_cvt(const float* __restrict__ in, unsigned short* __restrict__ out, int n4) {
  int i = blockIdx.x * blockDim.x + threadIdx.x;
  int stride = gridDim.x * blockDim.x;
  for (; i < n4; i += stride) {
    float4 v = ((const float4*)in)[i];
    ushort4 o = make_ushort4(f32_to_bf16(v.x), f32_to_bf16(v.y),
                             f32_to_bf16(v.z), f32_to_bf16(v.w));
    ((ushort4*)out)[i] = o;
  }
}

// ------------------------------------------- transpose + convert weights
// in: K x N f32 (row-major), out: N x K bf16 (row-major) == B^T
__global__ void k_transpose_cvt(const float* __restrict__ in, unsigned short* __restrict__ out,
                                int K, int N) {
  __shared__ float t[32][33];
  const int n0 = blockIdx.x * 32, k0 = blockIdx.y * 32;
  const int tx = threadIdx.x & 31, ty = threadIdx.x >> 5;  // 32 x 8
#pragma unroll
  for (int rr = 0; rr < 32; rr += 8)
    t[ty + rr][tx] = in[(size_t)(k0 + ty + rr) * N + n0 + tx];
  __syncthreads();
#pragma unroll
  for (int rr = 0; rr < 32; rr += 8)
    out[(size_t)(n0 + ty + rr) * K + k0 + tx] = f32_to_bf16(t[tx][ty + rr]);
}

// ----------------------------------------- fused bias+mask table (padded)
// bmt[w][h][i][j] (64x16x64x64 f32) = mask[w][i][j] + bias[h][i][j], -1e30 pad.
__global__ __launch_bounds__(256) void k_bm(const float* __restrict__ mask,
                                            const float* __restrict__ rel,
                                            float* __restrict__ bmt) {
  const int idx = blockIdx.x * 256 + threadIdx.x;   // w<<16 | h<<12 | i<<6 | j
  const int j = idx & 63, i = (idx >> 6) & 63, h = (idx >> 12) & 15, w = idx >> 16;
  float v = -1e30f;
  if (i < NWIN && j < NWIN) {
    const int rpi = ((j / 7) - (i / 7) + 6) * 13;
    v = mask[w * (NWIN * NWIN) + i * NWIN + j] + rel[rpi * NH + h];
  }
  bmt[idx] = v;
}

// ------------------------------------------------ GEMM (flatmm regime)
// C[M,N] = A[M,K](bf16) * BT[N,K]^T(bf16) + bias[N].   K == 512.
// Tall-skinny shape: B (<=1.5 MB) is L2-resident, A streamed once from HBM,
// C-write dominates -> HBM-bound.  So: NO LDS, NO barriers.  128x128 tile,
// 4 waves (2x2), each wave 64x64.  Both operands read straight to registers
// (bf16x8, one base pointer per frag row + immediate k offsets); the fully
// unrolled k-loop lets the compiler software-pipeline with vmcnt counters —
// no barrier to defeat its scheduling.
// SWAPPED mfma operands: acc[mi][nj] = mfma(b[nj], a[mi], acc) so the lane
// holds output n = 16nj+4lg+r (4 CONSECUTIVE columns), m = 16mi+lr
// (mapping verified by k_attn's S^T path) -> epilogue = 16 packed 8B (bf16)
// or 16B (f32) stores per lane instead of 128 scalar 2B stores.
template <int OUT_BF16>
__global__ __launch_bounds__(256, 3) void k_gemmd(const unsigned short* __restrict__ A,
                                                  const unsigned short* __restrict__ BT,
                                                  const float* __restrict__ bias,
                                                  void* __restrict__ Cout,
                                                  int M, int N) {
  const int tid = threadIdx.x;
  const int lane = tid & 63, wave = tid >> 6;
  const int wr = wave >> 1, wc = wave & 1;
  const int lr = lane & 15, lg = lane >> 4;

  // bijective XCD swizzle (gridDim.x % 8 == 0 at all call sites); bx fastest
  // so the gx blocks sharing an A-panel are consecutive on one XCD (L2 reuse).
  const int nwg = gridDim.x, q8 = nwg >> 3;
  const int wg = (blockIdx.x & 7) * q8 + (blockIdx.x >> 3);
  const int gx = N >> 7;
  const int bx = wg % gx, by = wg / gx;
  const int m0 = by << 7, n0 = bx << 7;

  // per-frag base pointers (k-offsets are compile-time immediates)
  const unsigned short* pa[4];
  const unsigned short* pb[4];
#pragma unroll
  for (int i = 0; i < 4; ++i) {
    pa[i] = A + (size_t)(m0 + wr * 64 + i * 16 + lr) * C_DIM + lg * 8;
    pb[i] = BT + (size_t)(n0 + wc * 64 + i * 16 + lr) * C_DIM + lg * 8;
  }

  const f32x4 fz = {0.f, 0.f, 0.f, 0.f};
  f32x4 acc[4][4];
#pragma unroll
  for (int i = 0; i < 4; ++i)
#pragma unroll
    for (int j = 0; j < 4; ++j) acc[i][j] = fz;

#pragma unroll
  for (int kk = 0; kk < 16; ++kk) {
    bf16x8 a_[4], b_[4];
#pragma unroll
    for (int i = 0; i < 4; ++i) a_[i] = *(const bf16x8*)(pa[i] + kk * 32);
#pragma unroll
    for (int j = 0; j < 4; ++j) b_[j] = *(const bf16x8*)(pb[j] + kk * 32);
#pragma unroll
    for (int mi = 0; mi < 4; ++mi)
#pragma unroll
      for (int nj = 0; nj < 4; ++nj)
        acc[mi][nj] = __builtin_amdgcn_mfma_f32_16x16x32_bf16(b_[nj], a_[mi], acc[mi][nj], 0, 0, 0);
  }

  // epilogue: lane holds rows m = 16mi+lr, cols n = 16nj+4lg+{0..3}
  f32x4 b4[4];
#pragma unroll
  for (int nj = 0; nj < 4; ++nj)
    b4[nj] = *(const f32x4*)(bias + n0 + wc * 64 + nj * 16 + 4 * lg);
#pragma unroll
  for (int mi = 0; mi < 4; ++mi) {
    const size_t row = (size_t)(m0 + wr * 64 + mi * 16 + lr);
#pragma unroll
    for (int nj = 0; nj < 4; ++nj) {
      const int colbase = n0 + wc * 64 + nj * 16 + 4 * lg;
      float v0 = acc[mi][nj][0] + b4[nj][0];
      float v1 = acc[mi][nj][1] + b4[nj][1];
      float v2 = acc[mi][nj][2] + b4[nj][2];
      float v3 = acc[mi][nj][3] + b4[nj][3];
      if (OUT_BF16) {
        uint2 st;
        st.x = (unsigned int)f32_to_bf16(v0) | ((unsigned int)f32_to_bf16(v1) << 16);
        st.y = (unsigned int)f32_to_bf16(v2) | ((unsigned int)f32_to_bf16(v3) << 16);
        *(uint2*)((unsigned short*)Cout + row * N + colbase) = st;
      } else {
        f32x4 st = {v0, v1, v2, v3};
        *(f32x4*)((float*)Cout + row * N + colbase) = st;
      }
    }
  }
}

// ------------------------------------------------------------- attention
// 4 waves/block, one (b,h) per wave, zero barriers (waves independent).
__global__ __launch_bounds__(256) void k_attn(const unsigned short* __restrict__ qkv,
                                              const float* __restrict__ bmt,
                                              unsigned short* __restrict__ aout) {
  const int wave = threadIdx.x >> 6, lane = threadIdx.x & 63;
  const int lr = lane & 15, lg = lane >> 4;
  const int idx = blockIdx.x * 4 + wave;
  const int b = idx >> 4, h = idx & 15, w = b & 63;

  __shared__ __align__(16) unsigned short Pl[4][2048];  // [32 rows][64] swizzled
  __shared__ __align__(16) unsigned short Vt[4][2112];  // V^T, stride 66
  unsigned short* pl = Pl[wave];
  unsigned short* vt = Vt[wave];

  const unsigned short* qp = qkv + (size_t)b * NWIN * QKV_N + h * HD;
  const unsigned short* kp = qp + C_DIM;
  const unsigned short* vp = qp + 2 * C_DIM;

  bf16x8 kf[4], qf[4];
#pragma unroll
  for (int t = 0; t < 4; ++t) {
    kf[t] = *(const bf16x8*)(kp + (size_t)(t * 16 + lr) * QKV_N + lg * 8);
    qf[t] = *(const bf16x8*)(qp + (size_t)(t * 16 + lr) * QKV_N + lg * 8);
  }

  const u32x4 zv = {0u, 0u, 0u, 0u};
#pragma unroll
  for (int c0 = 0; c0 < 4; ++c0) {
    const int c = c0 * 64 + lane;
    const int key = c >> 2, d0 = (c & 3) << 3;
    union { u32x4 v; unsigned short s[8]; } tmp;
    tmp.v = (key < NWIN) ? *(const u32x4*)(vp + (size_t)key * QKV_N + d0) : zv;
#pragma unroll
    for (int jj = 0; jj < 8; ++jj) vt[(d0 + jj) * 66 + key] = tmp.s[jj];
  }

  const f32x4 fz = {0.f, 0.f, 0.f, 0.f};
  f32x4 s[4][4];  // [mi = j-frag][ni = i-frag]
#pragma unroll
  for (int mi = 0; mi < 4; ++mi)
#pragma unroll
    for (int ni = 0; ni < 4; ++ni) s[mi][ni] = fz;
#pragma unroll
  for (int mi = 0; mi < 4; ++mi)
#pragma unroll
    for (int ni = 0; ni < 4; ++ni)
      s[mi][ni] = __builtin_amdgcn_mfma_f32_16x16x32_bf16(kf[mi], qf[ni], s[mi][ni], 0, 0, 0);

  union VU { unsigned int u[4]; bf16x8 v; };
  VU vfr[2][2];  // [nj][ks]
#pragma unroll
  for (int nj = 0; nj < 2; ++nj)
#pragma unroll
    for (int ks = 0; ks < 2; ++ks) {
      const int base = ((16 * nj + lr) * 66 + 32 * ks + 8 * lg) >> 1;
#pragma unroll
      for (int u = 0; u < 4; ++u) vfr[nj][ks].u[u] = ((const unsigned int*)vt)[base + u];
    }

  const float scale = 0.1767766952966369f;  // 32^-0.5
  const float* tbl = bmt + ((size_t)(w * NH + h) << 12);

  f32x4 o[4][2];
#pragma unroll
  for (int qi = 0; qi < 4; ++qi)
#pragma unroll
    for (int nj = 0; nj < 2; ++nj) o[qi][nj] = fz;

#pragma unroll
  for (int ni = 0; ni < 4; ++ni) {
    float v[16];
    float mx = -3e38f;
#pragma unroll
    for (int mi = 0; mi < 4; ++mi) {
      const f32x4 t4 = *(const f32x4*)(tbl + (16 * ni + lr) * 64 + 16 * mi + 4 * lg);
#pragma unroll
      for (int r = 0; r < 4; ++r) {
        v[mi * 4 + r] = fmaf(s[mi][ni][r], scale, t4[r]);
        mx = fmaxf(mx, v[mi * 4 + r]);
      }
    }
    mx = fmaxf(mx, __shfl_xor(mx, 16));
    mx = fmaxf(mx, __shfl_xor(mx, 32));
    float sum = 0.f;
#pragma unroll
    for (int t = 0; t < 16; ++t) {
      v[t] = __expf(v[t] - mx);
      sum += v[t];
    }
    sum += __shfl_xor(sum, 16);
    sum += __shfl_xor(sum, 32);
    const float inv = __builtin_amdgcn_rcpf(sum);

    const int ip = 16 * (ni & 1) + lr;
#pragma unroll
    for (int mi = 0; mi < 4; ++mi) {
      const unsigned int lo = (unsigned int)f32_to_bf16(v[mi * 4 + 0] * inv) |
                              ((unsigned int)f32_to_bf16(v[mi * 4 + 1] * inv) << 16);
      const unsigned int hi = (unsigned int)f32_to_bf16(v[mi * 4 + 2] * inv) |
                              ((unsigned int)f32_to_bf16(v[mi * 4 + 3] * inv) << 16);
      const int byteoff = 32 * mi + 8 * lg;
      const int sw = byteoff ^ ((ip & 7) << 4);
      uint2 w2; w2.x = lo; w2.y = hi;
      *(uint2*)((char*)pl + ip * 128 + sw) = w2;
    }

    if (ni & 1) {
      asm volatile("s_waitcnt lgkmcnt(0)" ::: "memory");
      __builtin_amdgcn_sched_barrier(0);
      const int half = ni >> 1;
#pragma unroll
      for (int q2 = 0; q2 < 2; ++q2) {
        const int qi = half * 2 + q2;
        const int ipr = 16 * q2 + lr;
#pragma unroll
        for (int ks = 0; ks < 2; ++ks) {
          const int bo = 64 * ks + 16 * lg;
          const int swr = bo ^ ((ipr & 7) << 4);
          const bf16x8 pa = *(const bf16x8*)((const char*)pl + ipr * 128 + swr);
#pragma unroll
          for (int nj = 0; nj < 2; ++nj)
            o[qi][nj] = __builtin_amdgcn_mfma_f32_16x16x32_bf16(pa, vfr[nj][ks].v, o[qi][nj], 0, 0, 0);
        }
      }
    }
  }

  const size_t orow = (size_t)b * NWIN;
#pragma unroll
  for (int qi = 0; qi < 4; ++qi)
#pragma unroll
    for (int r = 0; r < 4; ++r) {
      const int i = 16 * qi + 4 * lg + r;
      if (i < NWIN) {
#pragma unroll
        for (int nj = 0; nj < 2; ++nj)
          aout[(orow + i) * C_DIM + h * HD + 16 * nj + lr] = f32_to_bf16(o[qi][nj][r]);
      }
    }
}

// ---------------------------------------------------------------- launch
static const size_t SZ_QKV = (size_t)M_ROWS * QKV_N * 2;
static const size_t SZ_XB  = (size_t)M_ROWS * C_DIM * 2;
static const size_t SZ_WQ  = (size_t)QKV_N * C_DIM * 2;
static const size_t OFF_QKV = 0;
static const size_t OFF_XB  = OFF_QKV + SZ_QKV;   // x_bf16, later reused as attn_out
static const size_t OFF_WQ  = OFF_XB + SZ_XB;
static const size_t OFF_WP  = OFF_WQ + SZ_WQ;

extern "C" void kernel_launch(void* const* d_in, const int* in_sizes, int n_in,
                              void* d_out, int out_size, void* d_ws, size_t ws_size,
                              hipStream_t stream) {
  const float* x      = (const float*)d_in[0];
  const float* mask   = (const float*)d_in[1];
  const float* qkv_w  = (const float*)d_in[2];
  const float* qkv_b  = (const float*)d_in[3];
  const float* proj_w = (const float*)d_in[4];
  const float* proj_b = (const float*)d_in[5];
  const float* rel    = (const float*)d_in[6];
  float* out = (float*)d_out;

  char* ws = (char*)d_ws;
  unsigned short* qkvb = (unsigned short*)(ws + OFF_QKV);
  unsigned short* xb   = (unsigned short*)(ws + OFF_XB);
  unsigned short* wqT  = (unsigned short*)(ws + OFF_WQ);
  unsigned short* wpT  = (unsigned short*)(ws + OFF_WP);
  // bmt (16.78 MB) in d_out scratch: fully consumed by k_attn before final GEMM.
  float* bmt = (float*)d_out;

  k_cvt<<<2048, 256, 0, stream>>>(x, xb, M_ROWS * C_DIM / 4);
  k_transpose_cvt<<<dim3(QKV_N / 32, C_DIM / 32), 256, 0, stream>>>(qkv_w, wqT, C_DIM, QKV_N);
  k_transpose_cvt<<<dim3(C_DIM / 32, C_DIM / 32), 256, 0, stream>>>(proj_w, wpT, C_DIM, C_DIM);
  k_bm<<<(NMASK * NH * 64 * 64) / 256, 256, 0, stream>>>(mask, rel, bmt);

  // qkv = x @ qkv_w + qkv_b   (bf16 out), grid 784*12 = 9408 (%8==0)
  k_gemmd<1><<<(M_ROWS / 128) * (QKV_N / 128), 256, 0, stream>>>(
      xb, wqT, qkv_b, qkvb, M_ROWS, QKV_N);

  // attention -> attn_out (reuses xb region)
  k_attn<<<2048 * NH / 4, 256, 0, stream>>>(qkvb, bmt, xb);

  // out = attn_out @ proj_w + proj_b  (f32 out), grid 784*4 = 3136 (%8==0)
  k_gemmd<0><<<(M_ROWS / 128) * (C_DIM / 128), 256, 0, stream>>>(
      xb, wpT, proj_b, out, M_ROWS, C_DIM);
}

// Round 7
// 698.084 us; speedup vs baseline: 1.4336x; 1.4336x over previous
//
#include <hip/hip_runtime.h>
#include <hip/hip_bf16.h>
#include <stdint.h>

// Problem constants (match setup_inputs)
#define M_ROWS 100352   // 2048 * 49
#define C_DIM  512
#define QKV_N  1536
#define NH     16
#define HD     32
#define NWIN   49       // window tokens (7*7)
#define NMASK  64

typedef __attribute__((ext_vector_type(4))) float        f32x4;
typedef __attribute__((ext_vector_type(8))) short        bf16x8;
typedef __attribute__((ext_vector_type(4))) unsigned int u32x4;

static __device__ __forceinline__ unsigned short f32_to_bf16(float f) {
  union { float f; unsigned int u; } v; v.f = f;
  unsigned int u = v.u;
  return (unsigned short)((u + 0x7FFFu + ((u >> 16) & 1u)) >> 16);  // RNE
}

// global -> LDS direct DMA, 16B per lane. dest = wave-uniform base + lane*16.
static __device__ __forceinline__ void gload_lds16(const void* g, void* l) {
  __builtin_amdgcn_global_load_lds(
      (const __attribute__((address_space(1))) unsigned int*)g,
      (__attribute__((address_space(3))) unsigned int*)l, 16, 0, 0);
}

// ---------------------------------------------------------------- k_cvt
__global__ void k_cvt(const float* __restrict__ in, unsigned short* __restrict__ out, int n4) {
  int i = blockIdx.x * blockDim.x + threadIdx.x;
  int stride = gridDim.x * blockDim.x;
  for (; i < n4; i += stride) {
    float4 v = ((const float4*)in)[i];
    ushort4 o = make_ushort4(f32_to_bf16(v.x), f32_to_bf16(v.y),
                             f32_to_bf16(v.z), f32_to_bf16(v.w));
    ((ushort4*)out)[i] = o;
  }
}

// ------------------------------------------- transpose + convert weights
// in: K x N f32 (row-major), out: N x K bf16 (row-major) == B^T
__global__ void k_transpose_cvt(const float* __restrict__ in, unsigned short* __restrict__ out,
                                int K, int N) {
  __shared__ float t[32][33];
  const int n0 = blockIdx.x * 32, k0 = blockIdx.y * 32;
  const int tx = threadIdx.x & 31, ty = threadIdx.x >> 5;  // 32 x 8
#pragma unroll
  for (int rr = 0; rr < 32; rr += 8)
    t[ty + rr][tx] = in[(size_t)(k0 + ty + rr) * N + n0 + tx];
  __syncthreads();
#pragma unroll
  for (int rr = 0; rr < 32; rr += 8)
    out[(size_t)(n0 + ty + rr) * K + k0 + tx] = f32_to_bf16(t[tx][ty + rr]);
}

// ----------------------------------------- fused bias+mask table (padded)
// bmt[w][h][i][j] (64x16x64x64 f32) = mask[w][i][j] + bias[h][i][j], -1e30 pad.
__global__ __launch_bounds__(256) void k_bm(const float* __restrict__ mask,
                                            const float* __restrict__ rel,
                                            float* __restrict__ bmt) {
  const int idx = blockIdx.x * 256 + threadIdx.x;   // w<<16 | h<<12 | i<<6 | j
  const int j = idx & 63, i = (idx >> 6) & 63, h = (idx >> 12) & 15, w = idx >> 16;
  float v = -1e30f;
  if (i < NWIN && j < NWIN) {
    const int rpi = ((j / 7) - (i / 7) + 6) * 13;
    v = mask[w * (NWIN * NWIN) + i * NWIN + j] + rel[rpi * NH + h];
  }
  bmt[idx] = v;
}

#define WAITB(N)                                              \
  do {                                                        \
    asm volatile("s_waitcnt vmcnt(" #N ")" ::: "memory");     \
    __builtin_amdgcn_sched_barrier(0);                        \
    __builtin_amdgcn_s_barrier();                             \
    __builtin_amdgcn_sched_barrier(0);                        \
  } while (0)

// ------------------------------------------------------------------ GEMM
// C[M,N] = A[M,K=512](bf16) * BT[N,K]^T(bf16) + bias[N].
// 128x128 tile, BK=64, 4 waves (2x2, 64x64/wave), LDS 64 KB dbuf ->
// 2 blocks/CU (vs r5's 128KB/1-block: doubles latency-hiding TLP).
//
// LDS per op per tile: 16 subtiles (s = rg*2 + cg32; rg=row/16, cg32=col/32),
// subtile = [cg 0..3][row 0..15][8 col] (1 KB).  Conflict-free ds_read_b128
// (r4/r5: 0 SQ_LDS_BANK_CONFLICT).  gload_lds dest LINEAR (wave w writes
// subtile 4i+w, lane -> row lane&15, colgrp lane>>4); permutation carried by
// the per-lane GLOBAL source address.
//
// Pipeline = T3 minimum 2-phase with counted vmcnt: stage(t+1)'s 8 loads
// issued first, then vmcnt(8) drains exactly tile-t's 8 (FIFO), barrier,
// ds_read+MFMA, end barrier.  Never vmcnt(0) in main loop.
// WAR: stage(t+2) (iter t+1) overwrites buf[cur] read in iter t -> guarded
// by iter t's end barrier (frags already in regs: compiler's lgkmcnt waits
// precede MFMA issue).
//
// SWAPPED mfma operands (r6, verified): acc[mi][nj] = mfma(b, a, acc) ->
// lane holds cols n = 16nj+4lg+{0..3}, row m = 16mi+lr -> packed 8B/16B
// C-stores instead of 128 scalar 2B stores.
template <int OUT_BF16>
__global__ __launch_bounds__(256, 4) void k_gemm128(const unsigned short* __restrict__ A,
                                                    const unsigned short* __restrict__ BT,
                                                    const float* __restrict__ bias,
                                                    void* __restrict__ Cout,
                                                    int M, int N) {
  __shared__ __align__(16) unsigned short lds[2][2][8192];  // [buf][A|B] 64 KB
  const int tid = threadIdx.x;
  const int lane = tid & 63, wave = tid >> 6;
  const int wr = wave >> 1, wc = wave & 1;
  const int lr = lane & 15, lg = lane >> 4;

  // bijective XCD swizzle (gridDim.x % 8 == 0 at all call sites); bx fastest
  // so consecutive wgs on one XCD share an A panel (L2 reuse).
  const int nwg = gridDim.x, q8 = nwg >> 3;
  const int wg = (blockIdx.x & 7) * q8 + (blockIdx.x >> 3);
  const int gx = N >> 7;
  const int bx = wg % gx, by = wg / gx;
  const int m0 = by << 7, n0 = bx << 7;

  const int srow = lane & 15;          // staging: global row within row-group
  const int scol = (lane >> 4) * 8;    // staging: global col within 32-col grp

  const f32x4 fz = {0.f, 0.f, 0.f, 0.f};
  f32x4 acc[4][4];
#pragma unroll
  for (int i = 0; i < 4; ++i)
#pragma unroll
    for (int j = 0; j < 4; ++j) acc[i][j] = fz;

  const int NT = C_DIM >> 6;  // 8 K-tiles

  // stage one K-tile of both operands: 8 gload_lds per lane
  auto stage = [&](int t, int buf) {
    const int k0 = t << 6;
#pragma unroll
    for (int i = 0; i < 4; ++i) {
      const int s = 4 * i + wave;        // subtile 0..15
      const int rg = s >> 1, cg32 = s & 1;
      const size_t gc = (size_t)(k0 + cg32 * 32 + scol);
      gload_lds16(A + (size_t)(m0 + rg * 16 + srow) * C_DIM + gc,
                  &lds[buf][0][s * 512]);
      gload_lds16(BT + (size_t)(n0 + rg * 16 + srow) * C_DIM + gc,
                  &lds[buf][1][s * 512]);
    }
  };

  const int roff = lg * 128 + lr * 8;  // ushort offset within subtile

  stage(0, 0);
  for (int t = 0; t < NT; ++t) {
    const int cur = t & 1;
    if (t + 1 < NT) {
      stage(t + 1, cur ^ 1);
      WAITB(8);                        // drain tile t only; keep t+1 in flight
    } else {
      WAITB(0);
    }
    const unsigned short* la = lds[cur][0];
    const unsigned short* lb = lds[cur][1];
#pragma unroll
    for (int ks = 0; ks < 2; ++ks) {
      bf16x8 a_[4], b_[4];
#pragma unroll
      for (int mi = 0; mi < 4; ++mi)
        a_[mi] = *(const bf16x8*)(la + (((wr * 4 + mi) * 2 + ks) * 512) + roff);
#pragma unroll
      for (int nj = 0; nj < 4; ++nj)
        b_[nj] = *(const bf16x8*)(lb + (((wc * 4 + nj) * 2 + ks) * 512) + roff);
#pragma unroll
      for (int mi = 0; mi < 4; ++mi)
#pragma unroll
        for (int nj = 0; nj < 4; ++nj)
          acc[mi][nj] = __builtin_amdgcn_mfma_f32_16x16x32_bf16(b_[nj], a_[mi], acc[mi][nj], 0, 0, 0);
    }
    __builtin_amdgcn_s_barrier();      // readers done before stage(t+2) overwrites
    __builtin_amdgcn_sched_barrier(0);
  }

  // epilogue: lane holds rows m = 16mi+lr, cols n = 16nj+4lg+{0..3}
  f32x4 b4[4];
#pragma unroll
  for (int nj = 0; nj < 4; ++nj)
    b4[nj] = *(const f32x4*)(bias + n0 + wc * 64 + nj * 16 + 4 * lg);
#pragma unroll
  for (int mi = 0; mi < 4; ++mi) {
    const size_t row = (size_t)(m0 + wr * 64 + mi * 16 + lr);
#pragma unroll
    for (int nj = 0; nj < 4; ++nj) {
      const int colbase = n0 + wc * 64 + nj * 16 + 4 * lg;
      float v0 = acc[mi][nj][0] + b4[nj][0];
      float v1 = acc[mi][nj][1] + b4[nj][1];
      float v2 = acc[mi][nj][2] + b4[nj][2];
      float v3 = acc[mi][nj][3] + b4[nj][3];
      if (OUT_BF16) {
        uint2 st;
        st.x = (unsigned int)f32_to_bf16(v0) | ((unsigned int)f32_to_bf16(v1) << 16);
        st.y = (unsigned int)f32_to_bf16(v2) | ((unsigned int)f32_to_bf16(v3) << 16);
        *(uint2*)((unsigned short*)Cout + row * N + colbase) = st;
      } else {
        f32x4 st = {v0, v1, v2, v3};
        *(f32x4*)((float*)Cout + row * N + colbase) = st;
      }
    }
  }
}

// ------------------------------------------------------------- attention
// 4 waves/block, one (b,h) per wave, zero barriers (waves independent).
__global__ __launch_bounds__(256) void k_attn(const unsigned short* __restrict__ qkv,
                                              const float* __restrict__ bmt,
                                              unsigned short* __restrict__ aout) {
  const int wave = threadIdx.x >> 6, lane = threadIdx.x & 63;
  const int lr = lane & 15, lg = lane >> 4;
  const int idx = blockIdx.x * 4 + wave;
  const int b = idx >> 4, h = idx & 15, w = b & 63;

  __shared__ __align__(16) unsigned short Pl[4][2048];  // [32 rows][64] swizzled
  __shared__ __align__(16) unsigned short Vt[4][2112];  // V^T, stride 66
  unsigned short* pl = Pl[wave];
  unsigned short* vt = Vt[wave];

  const unsigned short* qp = qkv + (size_t)b * NWIN * QKV_N + h * HD;
  const unsigned short* kp = qp + C_DIM;
  const unsigned short* vp = qp + 2 * C_DIM;

  bf16x8 kf[4], qf[4];
#pragma unroll
  for (int t = 0; t < 4; ++t) {
    kf[t] = *(const bf16x8*)(kp + (size_t)(t * 16 + lr) * QKV_N + lg * 8);
    qf[t] = *(const bf16x8*)(qp + (size_t)(t * 16 + lr) * QKV_N + lg * 8);
  }

  const u32x4 zv = {0u, 0u, 0u, 0u};
#pragma unroll
  for (int c0 = 0; c0 < 4; ++c0) {
    const int c = c0 * 64 + lane;
    const int key = c >> 2, d0 = (c & 3) << 3;
    union { u32x4 v; unsigned short s[8]; } tmp;
    tmp.v = (key < NWIN) ? *(const u32x4*)(vp + (size_t)key * QKV_N + d0) : zv;
#pragma unroll
    for (int jj = 0; jj < 8; ++jj) vt[(d0 + jj) * 66 + key] = tmp.s[jj];
  }

  const f32x4 fz = {0.f, 0.f, 0.f, 0.f};
  f32x4 s[4][4];  // [mi = j-frag][ni = i-frag]
#pragma unroll
  for (int mi = 0; mi < 4; ++mi)
#pragma unroll
    for (int ni = 0; ni < 4; ++ni) s[mi][ni] = fz;
#pragma unroll
  for (int mi = 0; mi < 4; ++mi)
#pragma unroll
    for (int ni = 0; ni < 4; ++ni)
      s[mi][ni] = __builtin_amdgcn_mfma_f32_16x16x32_bf16(kf[mi], qf[ni], s[mi][ni], 0, 0, 0);

  union VU { unsigned int u[4]; bf16x8 v; };
  VU vfr[2][2];  // [nj][ks]
#pragma unroll
  for (int nj = 0; nj < 2; ++nj)
#pragma unroll
    for (int ks = 0; ks < 2; ++ks) {
      const int base = ((16 * nj + lr) * 66 + 32 * ks + 8 * lg) >> 1;
#pragma unroll
      for (int u = 0; u < 4; ++u) vfr[nj][ks].u[u] = ((const unsigned int*)vt)[base + u];
    }

  const float scale = 0.1767766952966369f;  // 32^-0.5
  const float* tbl = bmt + ((size_t)(w * NH + h) << 12);

  f32x4 o[4][2];
#pragma unroll
  for (int qi = 0; qi < 4; ++qi)
#pragma unroll
    for (int nj = 0; nj < 2; ++nj) o[qi][nj] = fz;

#pragma unroll
  for (int ni = 0; ni < 4; ++ni) {
    float v[16];
    float mx = -3e38f;
#pragma unroll
    for (int mi = 0; mi < 4; ++mi) {
      const f32x4 t4 = *(const f32x4*)(tbl + (16 * ni + lr) * 64 + 16 * mi + 4 * lg);
#pragma unroll
      for (int r = 0; r < 4; ++r) {
        v[mi * 4 + r] = fmaf(s[mi][ni][r], scale, t4[r]);
        mx = fmaxf(mx, v[mi * 4 + r]);
      }
    }
    mx = fmaxf(mx, __shfl_xor(mx, 16));
    mx = fmaxf(mx, __shfl_xor(mx, 32));
    float sum = 0.f;
#pragma unroll
    for (int t = 0; t < 16; ++t) {
      v[t] = __expf(v[t] - mx);
      sum += v[t];
    }
    sum += __shfl_xor(sum, 16);
    sum += __shfl_xor(sum, 32);
    const float inv = __builtin_amdgcn_rcpf(sum);

    const int ip = 16 * (ni & 1) + lr;
#pragma unroll
    for (int mi = 0; mi < 4; ++mi) {
      const unsigned int lo = (unsigned int)f32_to_bf16(v[mi * 4 + 0] * inv) |
                              ((unsigned int)f32_to_bf16(v[mi * 4 + 1] * inv) << 16);
      const unsigned int hi = (unsigned int)f32_to_bf16(v[mi * 4 + 2] * inv) |
                              ((unsigned int)f32_to_bf16(v[mi * 4 + 3] * inv) << 16);
      const int byteoff = 32 * mi + 8 * lg;
      const int sw = byteoff ^ ((ip & 7) << 4);
      uint2 w2; w2.x = lo; w2.y = hi;
      *(uint2*)((char*)pl + ip * 128 + sw) = w2;
    }

    if (ni & 1) {
      asm volatile("s_waitcnt lgkmcnt(0)" ::: "memory");
      __builtin_amdgcn_sched_barrier(0);
      const int half = ni >> 1;
#pragma unroll
      for (int q2 = 0; q2 < 2; ++q2) {
        const int qi = half * 2 + q2;
        const int ipr = 16 * q2 + lr;
#pragma unroll
        for (int ks = 0; ks < 2; ++ks) {
          const int bo = 64 * ks + 16 * lg;
          const int swr = bo ^ ((ipr & 7) << 4);
          const bf16x8 pa = *(const bf16x8*)((const char*)pl + ipr * 128 + swr);
#pragma unroll
          for (int nj = 0; nj < 2; ++nj)
            o[qi][nj] = __builtin_amdgcn_mfma_f32_16x16x32_bf16(pa, vfr[nj][ks].v, o[qi][nj], 0, 0, 0);
        }
      }
    }
  }

  const size_t orow = (size_t)b * NWIN;
#pragma unroll
  for (int qi = 0; qi < 4; ++qi)
#pragma unroll
    for (int r = 0; r < 4; ++r) {
      const int i = 16 * qi + 4 * lg + r;
      if (i < NWIN) {
#pragma unroll
        for (int nj = 0; nj < 2; ++nj)
          aout[(orow + i) * C_DIM + h * HD + 16 * nj + lr] = f32_to_bf16(o[qi][nj][r]);
      }
    }
}

// ---------------------------------------------------------------- launch
static const size_t SZ_QKV = (size_t)M_ROWS * QKV_N * 2;
static const size_t SZ_XB  = (size_t)M_ROWS * C_DIM * 2;
static const size_t SZ_WQ  = (size_t)QKV_N * C_DIM * 2;
static const size_t OFF_QKV = 0;
static const size_t OFF_XB  = OFF_QKV + SZ_QKV;   // x_bf16, later reused as attn_out
static const size_t OFF_WQ  = OFF_XB + SZ_XB;
static const size_t OFF_WP  = OFF_WQ + SZ_WQ;

extern "C" void kernel_launch(void* const* d_in, const int* in_sizes, int n_in,
                              void* d_out, int out_size, void* d_ws, size_t ws_size,
                              hipStream_t stream) {
  const float* x      = (const float*)d_in[0];
  const float* mask   = (const float*)d_in[1];
  const float* qkv_w  = (const float*)d_in[2];
  const float* qkv_b  = (const float*)d_in[3];
  const float* proj_w = (const float*)d_in[4];
  const float* proj_b = (const float*)d_in[5];
  const float* rel    = (const float*)d_in[6];
  float* out = (float*)d_out;

  char* ws = (char*)d_ws;
  unsigned short* qkvb = (unsigned short*)(ws + OFF_QKV);
  unsigned short* xb   = (unsigned short*)(ws + OFF_XB);
  unsigned short* wqT  = (unsigned short*)(ws + OFF_WQ);
  unsigned short* wpT  = (unsigned short*)(ws + OFF_WP);
  // bmt (16.78 MB) in d_out scratch: fully consumed by k_attn before final GEMM.
  float* bmt = (float*)d_out;

  k_cvt<<<2048, 256, 0, stream>>>(x, xb, M_ROWS * C_DIM / 4);
  k_transpose_cvt<<<dim3(QKV_N / 32, C_DIM / 32), 256, 0, stream>>>(qkv_w, wqT, C_DIM, QKV_N);
  k_transpose_cvt<<<dim3(C_DIM / 32, C_DIM / 32), 256, 0, stream>>>(proj_w, wpT, C_DIM, C_DIM);
  k_bm<<<(NMASK * NH * 64 * 64) / 256, 256, 0, stream>>>(mask, rel, bmt);

  // qkv = x @ qkv_w + qkv_b   (bf16 out), grid 784*12 = 9408 (%8==0)
  k_gemm128<1><<<(M_ROWS / 128) * (QKV_N / 128), 256, 0, stream>>>(
      xb, wqT, qkv_b, qkvb, M_ROWS, QKV_N);

  // attention -> attn_out (reuses xb region)
  k_attn<<<2048 * NH / 4, 256, 0, stream>>>(qkvb, bmt, xb);

  // out = attn_out @ proj_w + proj_b  (f32 out), grid 784*4 = 3136 (%8==0)
  k_gemm128<0><<<(M_ROWS / 128) * (C_DIM / 128), 256, 0, stream>>>(
      xb, wpT, proj_b, out, M_ROWS, C_DIM);
}

// Round 8
// 667.480 us; speedup vs baseline: 1.4993x; 1.0459x over previous
//
#include <hip/hip_runtime.h>
#include <hip/hip_bf16.h>
#include <stdint.h>

// Problem constants (match setup_inputs)
#define M_ROWS 100352   // 2048 * 49
#define C_DIM  512
#define QKV_N  1536
#define NH     16
#define HD     32
#define NWIN   49       // window tokens (7*7)
#define NMASK  64

typedef __attribute__((ext_vector_type(4))) float        f32x4;
typedef __attribute__((ext_vector_type(8))) short        bf16x8;
typedef __attribute__((ext_vector_type(4))) unsigned int u32x4;

static __device__ __forceinline__ unsigned short f32_to_bf16(float f) {
  union { float f; unsigned int u; } v; v.f = f;
  unsigned int u = v.u;
  return (unsigned short)((u + 0x7FFFu + ((u >> 16) & 1u)) >> 16);  // RNE
}

// global -> LDS direct DMA, 16B per lane. dest = wave-uniform base + lane*16.
static __device__ __forceinline__ void gload_lds16(const void* g, void* l) {
  __builtin_amdgcn_global_load_lds(
      (const __attribute__((address_space(1))) unsigned int*)g,
      (__attribute__((address_space(3))) unsigned int*)l, 16, 0, 0);
}

// ---------------------------------------------------------------- k_cvt
__global__ void k_cvt(const float* __restrict__ in, unsigned short* __restrict__ out, int n4) {
  int i = blockIdx.x * blockDim.x + threadIdx.x;
  int stride = gridDim.x * blockDim.x;
  for (; i < n4; i += stride) {
    float4 v = ((const float4*)in)[i];
    ushort4 o = make_ushort4(f32_to_bf16(v.x), f32_to_bf16(v.y),
                             f32_to_bf16(v.z), f32_to_bf16(v.w));
    ((ushort4*)out)[i] = o;
  }
}

// ------------------------------------------- transpose + convert weights
// in: K x N f32 (row-major), out: N x K bf16 (row-major) == B^T
__global__ void k_transpose_cvt(const float* __restrict__ in, unsigned short* __restrict__ out,
                                int K, int N) {
  __shared__ float t[32][33];
  const int n0 = blockIdx.x * 32, k0 = blockIdx.y * 32;
  const int tx = threadIdx.x & 31, ty = threadIdx.x >> 5;  // 32 x 8
#pragma unroll
  for (int rr = 0; rr < 32; rr += 8)
    t[ty + rr][tx] = in[(size_t)(k0 + ty + rr) * N + n0 + tx];
  __syncthreads();
#pragma unroll
  for (int rr = 0; rr < 32; rr += 8)
    out[(size_t)(n0 + ty + rr) * K + k0 + tx] = f32_to_bf16(t[tx][ty + rr]);
}

// ----------------------------------------- fused bias+mask table (padded)
// bmt[w][h][i][j] (64x16x64x64 f32) = mask[w][i][j] + bias[h][i][j], -1e30 pad.
__global__ __launch_bounds__(256) void k_bm(const float* __restrict__ mask,
                                            const float* __restrict__ rel,
                                            float* __restrict__ bmt) {
  const int idx = blockIdx.x * 256 + threadIdx.x;   // w<<16 | h<<12 | i<<6 | j
  const int j = idx & 63, i = (idx >> 6) & 63, h = (idx >> 12) & 15, w = idx >> 16;
  float v = -1e30f;
  if (i < NWIN && j < NWIN) {
    const int rpi = ((j / 7) - (i / 7) + 6) * 13;
    v = mask[w * (NWIN * NWIN) + i * NWIN + j] + rel[rpi * NH + h];
  }
  bmt[idx] = v;
}

#define WAITB(N)                                              \
  do {                                                        \
    asm volatile("s_waitcnt vmcnt(" #N ")" ::: "memory");     \
    __builtin_amdgcn_sched_barrier(0);                        \
    __builtin_amdgcn_s_barrier();                             \
    __builtin_amdgcn_sched_barrier(0);                        \
  } while (0)

// ------------------------------------------------------------------ GEMM
// C[M,N] = A[M,K=512](bf16) * BT[N,K]^T(bf16) + bias[N].
// BM=256, BN=128, BK=64.  512 threads = 8 waves (4M x 2N), each 64x64.
// 3 LDS buffers (144 KB) -> TWO-TILE-DEEP prefetch: stage(t+2) issued at top
// of iter t, so the vmcnt(12) wait drains loads issued TWO iterations ago
// (load latency fully off the critical path; waits are ~free in steady state).
//
// LDS per buffer: A = 32 subtiles, B = 16 subtiles; subtile = 16 rows x 32
// cols stored [cg 0..3][row 0..15][8 col] (1 KB) -> conflict-free b128 reads
// (r4-r7: 0 SQ_LDS_BANK_CONFLICT).  gload_lds dest LINEAR; permutation
// carried by per-lane GLOBAL source (row = lane&15, colgrp = lane>>4).
//
// Ledger: 6 loads/lane/tile (A 4 + B 2).  vmcnt(12) = tiles t+1,t+2 in
// flight.  Tail: t=NT-2 -> vmcnt(6), t=NT-1 -> vmcnt(0).  WAR: stage(t+2)
// writes buf[(t+2)%3], last read in iter t-1, guarded by t-1's end barrier.
// Loop unrolled (NT=8 compile-time) -> all buffer indices static.
//
// SWAPPED mfma operands (verified r6/r7): acc = mfma(b, a, acc) -> lane
// holds cols n = 16nj+4lg+{0..3}, rows m = 16mi+lr -> packed 8B/16B stores.
template <int OUT_BF16>
__global__ __launch_bounds__(512, 1) void k_gemm3(const unsigned short* __restrict__ A,
                                                  const unsigned short* __restrict__ BT,
                                                  const float* __restrict__ bias,
                                                  void* __restrict__ Cout,
                                                  int M, int N) {
  __shared__ __align__(16) unsigned short lds[3][24576];  // [buf][A:0..16383 | B:16384..]
  const int tid = threadIdx.x;
  const int lane = tid & 63, wave = tid >> 6;
  const int wr = wave >> 1, wc = wave & 1;      // 4M x 2N wave grid
  const int lr = lane & 15, lg = lane >> 4;

  // bijective XCD swizzle (gridDim.x % 8 == 0 at all call sites); bx fastest
  // so consecutive wgs on one XCD share an A panel (L2 reuse).
  const int nwg = gridDim.x, q8 = nwg >> 3;
  const int wg = (blockIdx.x & 7) * q8 + (blockIdx.x >> 3);
  const int gx = N >> 7;
  const int bx = wg % gx, by = wg / gx;
  const int m0 = by << 8, n0 = bx << 7;

  const int srow = lane & 15;          // staging: row within row-group
  const int scol = (lane >> 4) * 8;    // staging: col within 32-col group

  const f32x4 fz = {0.f, 0.f, 0.f, 0.f};
  f32x4 acc[4][4];
#pragma unroll
  for (int i = 0; i < 4; ++i)
#pragma unroll
    for (int j = 0; j < 4; ++j) acc[i][j] = fz;

  const int NT = C_DIM >> 6;  // 8 K-tiles (compile-time)

  // stage tile t into buffer buf: A 4 subtile-loads + B 2 per lane
  auto stage = [&](int t, int buf) {
    const int k0 = t << 6;
#pragma unroll
    for (int i = 0; i < 4; ++i) {
      const int s = wave + 8 * i;        // A subtile 0..31
      gload_lds16(A + (size_t)(m0 + (s >> 1) * 16 + srow) * C_DIM + k0 + (s & 1) * 32 + scol,
                  &lds[buf][s * 512]);
    }
#pragma unroll
    for (int i = 0; i < 2; ++i) {
      const int s = wave + 8 * i;        // B subtile 0..15
      gload_lds16(BT + (size_t)(n0 + (s >> 1) * 16 + srow) * C_DIM + k0 + (s & 1) * 32 + scol,
                  &lds[buf][16384 + s * 512]);
    }
  };

  const int roff = lg * 128 + lr * 8;  // ushort offset within subtile

  stage(0, 0);
  stage(1, 1);
#pragma unroll
  for (int t = 0; t < 8; ++t) {
    const int cur = t % 3;
    if (t < 6) {
      stage(t + 2, (t + 2) % 3);
      WAITB(12);                       // drain tile t (2 iters old); keep 12
    } else if (t == 6) {
      WAITB(6);                        // drain tile 6; keep tile 7's 6
    } else {
      WAITB(0);
    }
    const unsigned short* la = lds[cur];
    const unsigned short* lb = lds[cur] + 16384;
    bf16x8 a_[4][2], b_[4][2];
#pragma unroll
    for (int mi = 0; mi < 4; ++mi)
#pragma unroll
      for (int ks = 0; ks < 2; ++ks)
        a_[mi][ks] = *(const bf16x8*)(la + (((wr * 4 + mi) * 2 + ks) * 512) + roff);
#pragma unroll
    for (int nj = 0; nj < 4; ++nj)
#pragma unroll
      for (int ks = 0; ks < 2; ++ks)
        b_[nj][ks] = *(const bf16x8*)(lb + (((wc * 4 + nj) * 2 + ks) * 512) + roff);
    __builtin_amdgcn_s_setprio(1);
#pragma unroll
    for (int mi = 0; mi < 4; ++mi)
#pragma unroll
      for (int nj = 0; nj < 4; ++nj)
#pragma unroll
        for (int ks = 0; ks < 2; ++ks)
          acc[mi][nj] = __builtin_amdgcn_mfma_f32_16x16x32_bf16(b_[nj][ks], a_[mi][ks], acc[mi][nj], 0, 0, 0);
    __builtin_amdgcn_s_setprio(0);
    __builtin_amdgcn_s_barrier();      // readers done before stage(t+3) overwrites
    __builtin_amdgcn_sched_barrier(0);
  }

  // epilogue: lane holds rows m = 16mi+lr, cols n = 16nj+4lg+{0..3}
  f32x4 b4[4];
#pragma unroll
  for (int nj = 0; nj < 4; ++nj)
    b4[nj] = *(const f32x4*)(bias + n0 + wc * 64 + nj * 16 + 4 * lg);
#pragma unroll
  for (int mi = 0; mi < 4; ++mi) {
    const size_t row = (size_t)(m0 + wr * 64 + mi * 16 + lr);
#pragma unroll
    for (int nj = 0; nj < 4; ++nj) {
      const int colbase = n0 + wc * 64 + nj * 16 + 4 * lg;
      float v0 = acc[mi][nj][0] + b4[nj][0];
      float v1 = acc[mi][nj][1] + b4[nj][1];
      float v2 = acc[mi][nj][2] + b4[nj][2];
      float v3 = acc[mi][nj][3] + b4[nj][3];
      if (OUT_BF16) {
        uint2 st;
        st.x = (unsigned int)f32_to_bf16(v0) | ((unsigned int)f32_to_bf16(v1) << 16);
        st.y = (unsigned int)f32_to_bf16(v2) | ((unsigned int)f32_to_bf16(v3) << 16);
        *(uint2*)((unsigned short*)Cout + row * N + colbase) = st;
      } else {
        f32x4 st = {v0, v1, v2, v3};
        *(f32x4*)((float*)Cout + row * N + colbase) = st;
      }
    }
  }
}

// ------------------------------------------------------------- attention
// 4 waves/block, one (b,h) per wave, zero barriers (waves independent).
__global__ __launch_bounds__(256) void k_attn(const unsigned short* __restrict__ qkv,
                                              const float* __restrict__ bmt,
                                              unsigned short* __restrict__ aout) {
  const int wave = threadIdx.x >> 6, lane = threadIdx.x & 63;
  const int lr = lane & 15, lg = lane >> 4;
  const int idx = blockIdx.x * 4 + wave;
  const int b = idx >> 4, h = idx & 15, w = b & 63;

  __shared__ __align__(16) unsigned short Pl[4][2048];  // [32 rows][64] swizzled
  __shared__ __align__(16) unsigned short Vt[4][2112];  // V^T, stride 66
  unsigned short* pl = Pl[wave];
  unsigned short* vt = Vt[wave];

  const unsigned short* qp = qkv + (size_t)b * NWIN * QKV_N + h * HD;
  const unsigned short* kp = qp + C_DIM;
  const unsigned short* vp = qp + 2 * C_DIM;

  bf16x8 kf[4], qf[4];
#pragma unroll
  for (int t = 0; t < 4; ++t) {
    kf[t] = *(const bf16x8*)(kp + (size_t)(t * 16 + lr) * QKV_N + lg * 8);
    qf[t] = *(const bf16x8*)(qp + (size_t)(t * 16 + lr) * QKV_N + lg * 8);
  }

  const u32x4 zv = {0u, 0u, 0u, 0u};
#pragma unroll
  for (int c0 = 0; c0 < 4; ++c0) {
    const int c = c0 * 64 + lane;
    const int key = c >> 2, d0 = (c & 3) << 3;
    union { u32x4 v; unsigned short s[8]; } tmp;
    tmp.v = (key < NWIN) ? *(const u32x4*)(vp + (size_t)key * QKV_N + d0) : zv;
#pragma unroll
    for (int jj = 0; jj < 8; ++jj) vt[(d0 + jj) * 66 + key] = tmp.s[jj];
  }

  const f32x4 fz = {0.f, 0.f, 0.f, 0.f};
  f32x4 s[4][4];  // [mi = j-frag][ni = i-frag]
#pragma unroll
  for (int mi = 0; mi < 4; ++mi)
#pragma unroll
    for (int ni = 0; ni < 4; ++ni) s[mi][ni] = fz;
#pragma unroll
  for (int mi = 0; mi < 4; ++mi)
#pragma unroll
    for (int ni = 0; ni < 4; ++ni)
      s[mi][ni] = __builtin_amdgcn_mfma_f32_16x16x32_bf16(kf[mi], qf[ni], s[mi][ni], 0, 0, 0);

  union VU { unsigned int u[4]; bf16x8 v; };
  VU vfr[2][2];  // [nj][ks]
#pragma unroll
  for (int nj = 0; nj < 2; ++nj)
#pragma unroll
    for (int ks = 0; ks < 2; ++ks) {
      const int base = ((16 * nj + lr) * 66 + 32 * ks + 8 * lg) >> 1;
#pragma unroll
      for (int u = 0; u < 4; ++u) vfr[nj][ks].u[u] = ((const unsigned int*)vt)[base + u];
    }

  const float scale = 0.1767766952966369f;  // 32^-0.5
  const float* tbl = bmt + ((size_t)(w * NH + h) << 12);

  f32x4 o[4][2];
#pragma unroll
  for (int qi = 0; qi < 4; ++qi)
#pragma unroll
    for (int nj = 0; nj < 2; ++nj) o[qi][nj] = fz;

#pragma unroll
  for (int ni = 0; ni < 4; ++ni) {
    float v[16];
    float mx = -3e38f;
#pragma unroll
    for (int mi = 0; mi < 4; ++mi) {
      const f32x4 t4 = *(const f32x4*)(tbl + (16 * ni + lr) * 64 + 16 * mi + 4 * lg);
#pragma unroll
      for (int r = 0; r < 4; ++r) {
        v[mi * 4 + r] = fmaf(s[mi][ni][r], scale, t4[r]);
        mx = fmaxf(mx, v[mi * 4 + r]);
      }
    }
    mx = fmaxf(mx, __shfl_xor(mx, 16));
    mx = fmaxf(mx, __shfl_xor(mx, 32));
    float sum = 0.f;
#pragma unroll
    for (int t = 0; t < 16; ++t) {
      v[t] = __expf(v[t] - mx);
      sum += v[t];
    }
    sum += __shfl_xor(sum, 16);
    sum += __shfl_xor(sum, 32);
    const float inv = __builtin_amdgcn_rcpf(sum);

    const int ip = 16 * (ni & 1) + lr;
#pragma unroll
    for (int mi = 0; mi < 4; ++mi) {
      const unsigned int lo = (unsigned int)f32_to_bf16(v[mi * 4 + 0] * inv) |
                              ((unsigned int)f32_to_bf16(v[mi * 4 + 1] * inv) << 16);
      const unsigned int hi = (unsigned int)f32_to_bf16(v[mi * 4 + 2] * inv) |
                              ((unsigned int)f32_to_bf16(v[mi * 4 + 3] * inv) << 16);
      const int byteoff = 32 * mi + 8 * lg;
      const int sw = byteoff ^ ((ip & 7) << 4);
      uint2 w2; w2.x = lo; w2.y = hi;
      *(uint2*)((char*)pl + ip * 128 + sw) = w2;
    }

    if (ni & 1) {
      asm volatile("s_waitcnt lgkmcnt(0)" ::: "memory");
      __builtin_amdgcn_sched_barrier(0);
      const int half = ni >> 1;
#pragma unroll
      for (int q2 = 0; q2 < 2; ++q2) {
        const int qi = half * 2 + q2;
        const int ipr = 16 * q2 + lr;
#pragma unroll
        for (int ks = 0; ks < 2; ++ks) {
          const int bo = 64 * ks + 16 * lg;
          const int swr = bo ^ ((ipr & 7) << 4);
          const bf16x8 pa = *(const bf16x8*)((const char*)pl + ipr * 128 + swr);
#pragma unroll
          for (int nj = 0; nj < 2; ++nj)
            o[qi][nj] = __builtin_amdgcn_mfma_f32_16x16x32_bf16(pa, vfr[nj][ks].v, o[qi][nj], 0, 0, 0);
        }
      }
    }
  }

  const size_t orow = (size_t)b * NWIN;
#pragma unroll
  for (int qi = 0; qi < 4; ++qi)
#pragma unroll
    for (int r = 0; r < 4; ++r) {
      const int i = 16 * qi + 4 * lg + r;
      if (i < NWIN) {
#pragma unroll
        for (int nj = 0; nj < 2; ++nj)
          aout[(orow + i) * C_DIM + h * HD + 16 * nj + lr] = f32_to_bf16(o[qi][nj][r]);
      }
    }
}

// ---------------------------------------------------------------- launch
static const size_t SZ_QKV = (size_t)M_ROWS * QKV_N * 2;
static const size_t SZ_XB  = (size_t)M_ROWS * C_DIM * 2;
static const size_t SZ_WQ  = (size_t)QKV_N * C_DIM * 2;
static const size_t OFF_QKV = 0;
static const size_t OFF_XB  = OFF_QKV + SZ_QKV;   // x_bf16, later reused as attn_out
static const size_t OFF_WQ  = OFF_XB + SZ_XB;
static const size_t OFF_WP  = OFF_WQ + SZ_WQ;

extern "C" void kernel_launch(void* const* d_in, const int* in_sizes, int n_in,
                              void* d_out, int out_size, void* d_ws, size_t ws_size,
                              hipStream_t stream) {
  const float* x      = (const float*)d_in[0];
  const float* mask   = (const float*)d_in[1];
  const float* qkv_w  = (const float*)d_in[2];
  const float* qkv_b  = (const float*)d_in[3];
  const float* proj_w = (const float*)d_in[4];
  const float* proj_b = (const float*)d_in[5];
  const float* rel    = (const float*)d_in[6];
  float* out = (float*)d_out;

  char* ws = (char*)d_ws;
  unsigned short* qkvb = (unsigned short*)(ws + OFF_QKV);
  unsigned short* xb   = (unsigned short*)(ws + OFF_XB);
  unsigned short* wqT  = (unsigned short*)(ws + OFF_WQ);
  unsigned short* wpT  = (unsigned short*)(ws + OFF_WP);
  // bmt (16.78 MB) in d_out scratch: fully consumed by k_attn before final GEMM.
  float* bmt = (float*)d_out;

  k_cvt<<<2048, 256, 0, stream>>>(x, xb, M_ROWS * C_DIM / 4);
  k_transpose_cvt<<<dim3(QKV_N / 32, C_DIM / 32), 256, 0, stream>>>(qkv_w, wqT, C_DIM, QKV_N);
  k_transpose_cvt<<<dim3(C_DIM / 32, C_DIM / 32), 256, 0, stream>>>(proj_w, wpT, C_DIM, C_DIM);
  k_bm<<<(NMASK * NH * 64 * 64) / 256, 256, 0, stream>>>(mask, rel, bmt);

  // qkv = x @ qkv_w + qkv_b   (bf16 out), grid 392*12 = 4704 (%8==0)
  k_gemm3<1><<<(M_ROWS / 256) * (QKV_N / 128), 512, 0, stream>>>(
      xb, wqT, qkv_b, qkvb, M_ROWS, QKV_N);

  // attention -> attn_out (reuses xb region)
  k_attn<<<2048 * NH / 4, 256, 0, stream>>>(qkvb, bmt, xb);

  // out = attn_out @ proj_w + proj_b  (f32 out), grid 392*4 = 1568 (%8==0)
  k_gemm3<0><<<(M_ROWS / 256) * (C_DIM / 128), 512, 0, stream>>>(
      xb, wpT, proj_b, out, M_ROWS, C_DIM);
}